// Round 3
// baseline (136.764 us; speedup 1.0000x reference)
//
#include <hip/hip_runtime.h>
#include <math.h>

#define CCH 3
#define BB 32
#define TT 128000
#define TSUB 1000
#define TFUL 8000
#define EPSV 1e-8f

#define NF4 (TT / 4)            // 32000 float4 per (b, channel)
#define BLK_PER_B 56            // divisible by 4 -> float4 finalize reads
#define STRIDE (BLK_PER_B * 256)

#define DIAR_SPLIT 4
#define ROWS_PER_DIAR (TSUB / DIAR_SPLIT)   // 250

#define NBLK_SISNR (BB * BLK_PER_B)         // 1792
#define NBLK_DIAR  (BB * DIAR_SPLIT)        // 128
#define NBLK_TOTAL (NBLK_SISNR + NBLK_DIAR) // 1920 (<= 2048 = all co-resident)

// ws layout (floats), TRANSPOSED so finalize reads contiguous runs:
//   [SP_OFF + k*NBLK_SISNR + sblk] : sisnr partial k of sisnr-block sblk
//   [DP_OFF + k*NBLK_DIAR  + dblk] : diar  partial k of diar-block dblk
// Every slot written exactly once per launch -> no zeroing, no atomics.
#define SP_OFF 0
#define DP_OFF (21 * NBLK_SISNR)

typedef float f32x4 __attribute__((ext_vector_type(4)));

__device__ __forceinline__ f32x4 ntload(const f32x4* p) {
    return __builtin_nontemporal_load(p);
}

__global__ __launch_bounds__(256) void stats_eendss(
    const float* __restrict__ sep, const float* __restrict__ src,
    const float* __restrict__ diar, const float* __restrict__ labels,
    float* __restrict__ ws) {
    const int lane = threadIdx.x & 63;
    const int wave = threadIdx.x >> 6;

    if (blockIdx.x >= NBLK_DIAR) {
        // ---------------- SI-SNR moment accumulation ----------------
        const int sblk = blockIdx.x - NBLK_DIAR;
        const int b = sblk / BLK_PER_B;
        const int chunk = sblk % BLK_PER_B;

        const f32x4* sA0 = (const f32x4*)(sep + (size_t)b * 3 * TT);
        const f32x4* sA1 = sA0 + NF4;
        const f32x4* sA2 = sA1 + NF4;
        const f32x4* sB0 = (const f32x4*)(src + (size_t)b * 3 * TT);
        const f32x4* sB1 = sB0 + NF4;
        const f32x4* sB2 = sB1 + NF4;

        float acc[21];
#pragma unroll
        for (int k = 0; k < 21; ++k) acc[k] = 0.0f;

        for (int i = chunk * 256 + threadIdx.x; i < NF4; i += STRIDE) {
            f32x4 xa = ntload(sA0 + i), xb = ntload(sA1 + i), xc = ntload(sA2 + i);
            f32x4 ya = ntload(sB0 + i), yb = ntload(sB1 + i), yc = ntload(sB2 + i);
            float sv[3][4] = {{xa.x, xa.y, xa.z, xa.w},
                              {xb.x, xb.y, xb.z, xb.w},
                              {xc.x, xc.y, xc.z, xc.w}};
            float tv[3][4] = {{ya.x, ya.y, ya.z, ya.w},
                              {yb.x, yb.y, yb.z, yb.w},
                              {yc.x, yc.y, yc.z, yc.w}};
#pragma unroll
            for (int e = 0; e < 4; ++e) {
                float s0 = sv[0][e], s1 = sv[1][e], s2 = sv[2][e];
                float t0 = tv[0][e], t1 = tv[1][e], t2 = tv[2][e];
                acc[0] += s0;  acc[1] += s1;  acc[2] += s2;
                acc[3] += s0 * s0;  acc[4] += s1 * s1;  acc[5] += s2 * s2;
                acc[6] += t0;  acc[7] += t1;  acc[8] += t2;
                acc[9] += t0 * t0;  acc[10] += t1 * t1;  acc[11] += t2 * t2;
                acc[12] += s0 * t0; acc[13] += s0 * t1; acc[14] += s0 * t2;
                acc[15] += s1 * t0; acc[16] += s1 * t1; acc[17] += s1 * t2;
                acc[18] += s2 * t0; acc[19] += s2 * t1; acc[20] += s2 * t2;
            }
        }

#pragma unroll
        for (int k = 0; k < 21; ++k) {
            float v = acc[k];
            v += __shfl_down(v, 32);
            v += __shfl_down(v, 16);
            v += __shfl_down(v, 8);
            v += __shfl_down(v, 4);
            v += __shfl_down(v, 2);
            v += __shfl_down(v, 1);
            acc[k] = v;
        }
        __shared__ float smem_s[4][21];
        if (lane == 0) {
#pragma unroll
            for (int k = 0; k < 21; ++k) smem_s[wave][k] = acc[k];
        }
        __syncthreads();
        if (threadIdx.x < 21) {
            float v = smem_s[0][threadIdx.x] + smem_s[1][threadIdx.x] +
                      smem_s[2][threadIdx.x] + smem_s[3][threadIdx.x];
            ws[SP_OFF + threadIdx.x * NBLK_SISNR + sblk] = v;
        }
    } else {
        // ---------------- diar BCE accumulation (launched FIRST:
        // latency-bound, hides under the BW-bound sisnr phase) -------
        const int blk = blockIdx.x;
        const int b = blk / DIAR_SPLIT;
        const int part = blk % DIAR_SPLIT;
        const int t0 = part * ROWS_PER_DIAR;
        const int tend = t0 + ROWS_PER_DIAR;

        float acc[12];
#pragma unroll
        for (int k = 0; k < 12; ++k) acc[k] = 0.0f;

        for (int t = t0 + threadIdx.x; t < tend; t += 256) {
            const float* dp = diar + ((size_t)b * TSUB + t) * 3;
            float lp[3], l1m[3];
#pragma unroll
            for (int i = 0; i < 3; ++i) {
                float p = dp[i];
                lp[i] = fmaxf(logf(p), -100.0f);
                l1m[i] = fmaxf(logf(1.0f - p), -100.0f);
                acc[i] += l1m[i];
            }
            const float* lb = labels + ((size_t)b * TFUL + (size_t)t * 8) * 3;
            float td0 = lb[0], td1 = lb[1], td2 = lb[2];
#pragma unroll
            for (int i = 0; i < 3; ++i) {
                float d = lp[i] - l1m[i];
                acc[3 + i * 3 + 0] += d * td0;
                acc[3 + i * 3 + 1] += d * td1;
                acc[3 + i * 3 + 2] += d * td2;
            }
        }

#pragma unroll
        for (int k = 0; k < 12; ++k) {
            float v = acc[k];
            v += __shfl_down(v, 32);
            v += __shfl_down(v, 16);
            v += __shfl_down(v, 8);
            v += __shfl_down(v, 4);
            v += __shfl_down(v, 2);
            v += __shfl_down(v, 1);
            acc[k] = v;
        }
        __shared__ float smem_d[4][12];
        if (lane == 0) {
#pragma unroll
            for (int k = 0; k < 12; ++k) smem_d[wave][k] = acc[k];
        }
        __syncthreads();
        if (threadIdx.x < 12) {
            float v = smem_d[0][threadIdx.x] + smem_d[1][threadIdx.x] +
                      smem_d[2][threadIdx.x] + smem_d[3][threadIdx.x];
            ws[DP_OFF + threadIdx.x * NBLK_DIAR + blk] = v;
        }
    }
}

__global__ __launch_bounds__(256) void finalize(
    const float* __restrict__ ws, const float* __restrict__ exist,
    const int* __restrict__ nspk_arr, float* __restrict__ out) {
    // shs[k][b]: lane b hits bank b for every k -> conflict-free
    __shared__ float shs[21][BB];
    __shared__ float shd[12][BB];

    // sum sisnr partials: run of BLK_PER_B floats = BLK_PER_B/4 float4s
    for (int idx = threadIdx.x; idx < 21 * BB; idx += 256) {
        const int k = idx / BB, b = idx % BB;
        const f32x4* p = (const f32x4*)(ws + SP_OFF + (size_t)k * NBLK_SISNR +
                                        b * BLK_PER_B);
        f32x4 v4 = p[0];
#pragma unroll
        for (int c = 1; c < BLK_PER_B / 4; ++c) {
            f32x4 t = p[c];
            v4.x += t.x; v4.y += t.y; v4.z += t.z; v4.w += t.w;
        }
        shs[k][b] = v4.x + v4.y + v4.z + v4.w;
    }
    // sum diar partials: one float4 per (k,b)
    for (int idx = threadIdx.x; idx < 12 * BB; idx += 256) {
        const int k = idx / BB, b = idx % BB;
        const f32x4* p = (const f32x4*)(ws + DP_OFF + (size_t)k * NBLK_DIAR +
                                        b * DIAR_SPLIT);
        f32x4 v4 = p[0];
        shd[k][b] = v4.x + v4.y + v4.z + v4.w;
    }
    __syncthreads();

    float loss_s = 0.0f, loss_d = 0.0f, loss_e = 0.0f;
    if (threadIdx.x < BB) {
        const int b = threadIdx.x;
        const float invT = 1.0f / (float)TT;
        float est_sq[3], tgt_sq[3];
#pragma unroll
        for (int i = 0; i < 3; ++i)
            est_sq[i] = shs[3 + i][b] - shs[i][b] * shs[i][b] * invT;
#pragma unroll
        for (int j = 0; j < 3; ++j)
            tgt_sq[j] = shs[9 + j][b] - shs[6 + j][b] * shs[6 + j][b] * invT;

        float S[3][3];
#pragma unroll
        for (int i = 0; i < 3; ++i) {
#pragma unroll
            for (int j = 0; j < 3; ++j) {
                float dot = shs[12 + i * 3 + j][b] - shs[i][b] * shs[6 + j][b] * invT;
                float alpha = dot / (tgt_sq[j] + EPSV);
                float a2t = alpha * alpha * tgt_sq[j];
                float sig = a2t + EPSV;
                float noise = est_sq[i] - 2.0f * alpha * dot + a2t + EPSV;
                S[i][j] = 10.0f * log10f(sig / noise);
            }
        }

        float D[3][3];
#pragma unroll
        for (int i = 0; i < 3; ++i)
#pragma unroll
            for (int j = 0; j < 3; ++j)
                D[i][j] = -(shd[3 + i * 3 + j][b] + shd[i][b]) / (float)TSUB;

        const int ns_raw = nspk_arr[b];
        const int n_spk = min(max(ns_raw, 1), 3);

        const int P[6][3] = {{0, 1, 2}, {0, 2, 1}, {1, 0, 2},
                             {1, 2, 0}, {2, 0, 1}, {2, 1, 0}};
        float best_s = 3.0e38f, best_d = 3.0e38f;
        for (int p = 0; p < 6; ++p) {
            bool valid = true;
            for (int s = 0; s < 3; ++s)
                if (!((P[p][s] < n_spk) || (s >= n_spk))) valid = false;
            if (!valid) continue;
            float ssum = 0.0f, dsum = 0.0f;
            for (int s = 0; s < 3; ++s) {
                if (s < n_spk) {
                    ssum += S[P[p][s]][s];
                    dsum += D[P[p][s]][s];
                }
            }
            float inv_n = 1.0f / (float)n_spk;
            best_s = fminf(best_s, -(ssum * inv_n));
            best_d = fminf(best_d, dsum * inv_n);
        }
        loss_s = best_s;
        loss_d = best_d;

        const int n_ex = min(ns_raw, 3);
        float be = 0.0f;
#pragma unroll
        for (int j = 0; j < 4; ++j) {
            float p = exist[b * 4 + j];
            float tgt = (j < n_ex) ? 1.0f : 0.0f;
            float lpv = fmaxf(logf(p), -100.0f);
            float l1v = fmaxf(logf(1.0f - p), -100.0f);
            be += -(tgt * lpv + (1.0f - tgt) * l1v);
        }
        loss_e = be;
    }

    // wave-0 reduction (lanes 32..63 hold zeros; other waves ignored)
    loss_s += __shfl_down(loss_s, 32);
    loss_s += __shfl_down(loss_s, 16);
    loss_s += __shfl_down(loss_s, 8);
    loss_s += __shfl_down(loss_s, 4);
    loss_s += __shfl_down(loss_s, 2);
    loss_s += __shfl_down(loss_s, 1);
    loss_d += __shfl_down(loss_d, 32);
    loss_d += __shfl_down(loss_d, 16);
    loss_d += __shfl_down(loss_d, 8);
    loss_d += __shfl_down(loss_d, 4);
    loss_d += __shfl_down(loss_d, 2);
    loss_d += __shfl_down(loss_d, 1);
    loss_e += __shfl_down(loss_e, 32);
    loss_e += __shfl_down(loss_e, 16);
    loss_e += __shfl_down(loss_e, 8);
    loss_e += __shfl_down(loss_e, 4);
    loss_e += __shfl_down(loss_e, 2);
    loss_e += __shfl_down(loss_e, 1);

    if (threadIdx.x == 0) {
        float ls = loss_s / (float)BB;
        float ld = loss_d / (float)BB;
        float le = loss_e / (float)(BB * 4);
        out[0] = ls + 0.2f * ld + 0.2f * le;  // total
        out[1] = ls;                           // loss_sisnr
        out[2] = ld;                           // loss_diar
        out[3] = le;                           // loss_exist
        out[4] = -ls;                          // mean_sisnr
    }
}

extern "C" void kernel_launch(void* const* d_in, const int* in_sizes, int n_in,
                              void* d_out, int out_size, void* d_ws, size_t ws_size,
                              hipStream_t stream) {
    const float* separated = (const float*)d_in[0];
    const float* diar      = (const float*)d_in[1];
    const float* exist     = (const float*)d_in[2];
    const float* sources   = (const float*)d_in[3];
    const float* labels    = (const float*)d_in[4];
    const int*   nspk      = (const int*)d_in[5];
    float* out = (float*)d_out;
    float* ws  = (float*)d_ws;

    stats_eendss<<<NBLK_TOTAL, 256, 0, stream>>>(separated, sources, diar,
                                                 labels, ws);
    finalize<<<1, 256, 0, stream>>>(ws, exist, nspk, out);
}

// Round 4
// 130.757 us; speedup vs baseline: 1.0459x; 1.0459x over previous
//
#include <hip/hip_runtime.h>
#include <math.h>

#define CCH 3
#define BB 32
#define TT 128000
#define TSUB 1000
#define TFUL 8000
#define EPSV 1e-8f

#define NF4 (TT / 4)            // 32000 float4 per (b, channel)
#define BLK_PER_B 40
#define STRIDE (BLK_PER_B * 256)

#define DIAR_SPLIT 4
#define ROWS_PER_DIAR (TSUB / DIAR_SPLIT)   // 250

#define NBLK_SISNR (BB * BLK_PER_B)         // 1280
#define NBLK_DIAR  (BB * DIAR_SPLIT)        // 128
#define NBLK_TOTAL (NBLK_SISNR + NBLK_DIAR) // 1408

// ws layout (floats), TRANSPOSED so finalize reads contiguous runs:
//   [SP_OFF + k*NBLK_SISNR + blk] : sisnr partial k of block blk
//   [DP_OFF + k*NBLK_DIAR  + blk] : diar  partial k of block blk
// No zeroing needed: every slot is written exactly once per launch.
#define SP_OFF 0
#define DP_OFF (21 * NBLK_SISNR)

__global__ __launch_bounds__(256) void stats_eendss(
    const float* __restrict__ sep, const float* __restrict__ src,
    const float* __restrict__ diar, const float* __restrict__ labels,
    float* __restrict__ ws) {
    const int lane = threadIdx.x & 63;
    const int wave = threadIdx.x >> 6;

    if (blockIdx.x < NBLK_SISNR) {
        // ---------------- SI-SNR moment accumulation ----------------
        const int b = blockIdx.x / BLK_PER_B;
        const int chunk = blockIdx.x % BLK_PER_B;

        const float4* sA0 = (const float4*)(sep + (size_t)b * 3 * TT);
        const float4* sA1 = sA0 + NF4;
        const float4* sA2 = sA1 + NF4;
        const float4* sB0 = (const float4*)(src + (size_t)b * 3 * TT);
        const float4* sB1 = sB0 + NF4;
        const float4* sB2 = sB1 + NF4;

        float acc[21];
#pragma unroll
        for (int k = 0; k < 21; ++k) acc[k] = 0.0f;

        for (int i = chunk * 256 + threadIdx.x; i < NF4; i += STRIDE) {
            float4 xa = sA0[i], xb = sA1[i], xc = sA2[i];
            float4 ya = sB0[i], yb = sB1[i], yc = sB2[i];
            float sv[3][4] = {{xa.x, xa.y, xa.z, xa.w},
                              {xb.x, xb.y, xb.z, xb.w},
                              {xc.x, xc.y, xc.z, xc.w}};
            float tv[3][4] = {{ya.x, ya.y, ya.z, ya.w},
                              {yb.x, yb.y, yb.z, yb.w},
                              {yc.x, yc.y, yc.z, yc.w}};
#pragma unroll
            for (int e = 0; e < 4; ++e) {
                float s0 = sv[0][e], s1 = sv[1][e], s2 = sv[2][e];
                float t0 = tv[0][e], t1 = tv[1][e], t2 = tv[2][e];
                acc[0] += s0;  acc[1] += s1;  acc[2] += s2;
                acc[3] += s0 * s0;  acc[4] += s1 * s1;  acc[5] += s2 * s2;
                acc[6] += t0;  acc[7] += t1;  acc[8] += t2;
                acc[9] += t0 * t0;  acc[10] += t1 * t1;  acc[11] += t2 * t2;
                acc[12] += s0 * t0; acc[13] += s0 * t1; acc[14] += s0 * t2;
                acc[15] += s1 * t0; acc[16] += s1 * t1; acc[17] += s1 * t2;
                acc[18] += s2 * t0; acc[19] += s2 * t1; acc[20] += s2 * t2;
            }
        }

#pragma unroll
        for (int k = 0; k < 21; ++k) {
            float v = acc[k];
            v += __shfl_down(v, 32);
            v += __shfl_down(v, 16);
            v += __shfl_down(v, 8);
            v += __shfl_down(v, 4);
            v += __shfl_down(v, 2);
            v += __shfl_down(v, 1);
            acc[k] = v;
        }
        __shared__ float smem_s[4][21];
        if (lane == 0) {
#pragma unroll
            for (int k = 0; k < 21; ++k) smem_s[wave][k] = acc[k];
        }
        __syncthreads();
        if (threadIdx.x < 21) {
            float v = smem_s[0][threadIdx.x] + smem_s[1][threadIdx.x] +
                      smem_s[2][threadIdx.x] + smem_s[3][threadIdx.x];
            ws[SP_OFF + threadIdx.x * NBLK_SISNR + blockIdx.x] = v;
        }
    } else {
        // ---------------- diar BCE accumulation ----------------
        const int blk = blockIdx.x - NBLK_SISNR;
        const int b = blk / DIAR_SPLIT;
        const int part = blk % DIAR_SPLIT;
        const int t0 = part * ROWS_PER_DIAR;
        const int tend = t0 + ROWS_PER_DIAR;

        float acc[12];
#pragma unroll
        for (int k = 0; k < 12; ++k) acc[k] = 0.0f;

        for (int t = t0 + threadIdx.x; t < tend; t += 256) {
            const float* dp = diar + ((size_t)b * TSUB + t) * 3;
            float lp[3], l1m[3];
#pragma unroll
            for (int i = 0; i < 3; ++i) {
                float p = dp[i];
                lp[i] = fmaxf(logf(p), -100.0f);
                l1m[i] = fmaxf(logf(1.0f - p), -100.0f);
                acc[i] += l1m[i];
            }
            const float* lb = labels + ((size_t)b * TFUL + (size_t)t * 8) * 3;
            float td0 = lb[0], td1 = lb[1], td2 = lb[2];
#pragma unroll
            for (int i = 0; i < 3; ++i) {
                float d = lp[i] - l1m[i];
                acc[3 + i * 3 + 0] += d * td0;
                acc[3 + i * 3 + 1] += d * td1;
                acc[3 + i * 3 + 2] += d * td2;
            }
        }

#pragma unroll
        for (int k = 0; k < 12; ++k) {
            float v = acc[k];
            v += __shfl_down(v, 32);
            v += __shfl_down(v, 16);
            v += __shfl_down(v, 8);
            v += __shfl_down(v, 4);
            v += __shfl_down(v, 2);
            v += __shfl_down(v, 1);
            acc[k] = v;
        }
        __shared__ float smem_d[4][12];
        if (lane == 0) {
#pragma unroll
            for (int k = 0; k < 12; ++k) smem_d[wave][k] = acc[k];
        }
        __syncthreads();
        if (threadIdx.x < 12) {
            float v = smem_d[0][threadIdx.x] + smem_d[1][threadIdx.x] +
                      smem_d[2][threadIdx.x] + smem_d[3][threadIdx.x];
            ws[DP_OFF + threadIdx.x * NBLK_DIAR + blk] = v;
        }
    }
}

__global__ __launch_bounds__(256) void finalize(
    const float* __restrict__ ws, const float* __restrict__ exist,
    const int* __restrict__ nspk_arr, float* __restrict__ out) {
    // shs[k][b]: lane b reads bank b for every k -> conflict-free
    __shared__ float shs[21][BB];
    __shared__ float shd[12][BB];

    // sum sisnr partials: (k,b) pair per thread, 40 contiguous floats each
    for (int idx = threadIdx.x; idx < 21 * BB; idx += 256) {
        const int k = idx / BB, b = idx % BB;
        const float* p = ws + SP_OFF + (size_t)k * NBLK_SISNR + b * BLK_PER_B;
        float v = 0.0f;
#pragma unroll
        for (int c = 0; c < BLK_PER_B; ++c) v += p[c];
        shs[k][b] = v;
    }
    // sum diar partials: 4 contiguous floats each
    for (int idx = threadIdx.x; idx < 12 * BB; idx += 256) {
        const int k = idx / BB, b = idx % BB;
        const float* p = ws + DP_OFF + (size_t)k * NBLK_DIAR + b * DIAR_SPLIT;
        float v = 0.0f;
#pragma unroll
        for (int c = 0; c < DIAR_SPLIT; ++c) v += p[c];
        shd[k][b] = v;
    }
    __syncthreads();

    float loss_s = 0.0f, loss_d = 0.0f, loss_e = 0.0f;
    if (threadIdx.x < BB) {
        const int b = threadIdx.x;
        const float invT = 1.0f / (float)TT;
        float est_sq[3], tgt_sq[3];
#pragma unroll
        for (int i = 0; i < 3; ++i)
            est_sq[i] = shs[3 + i][b] - shs[i][b] * shs[i][b] * invT;
#pragma unroll
        for (int j = 0; j < 3; ++j)
            tgt_sq[j] = shs[9 + j][b] - shs[6 + j][b] * shs[6 + j][b] * invT;

        float S[3][3];
#pragma unroll
        for (int i = 0; i < 3; ++i) {
#pragma unroll
            for (int j = 0; j < 3; ++j) {
                float dot = shs[12 + i * 3 + j][b] - shs[i][b] * shs[6 + j][b] * invT;
                float alpha = dot / (tgt_sq[j] + EPSV);
                float a2t = alpha * alpha * tgt_sq[j];
                float sig = a2t + EPSV;
                float noise = est_sq[i] - 2.0f * alpha * dot + a2t + EPSV;
                S[i][j] = 10.0f * log10f(sig / noise);
            }
        }

        float D[3][3];
#pragma unroll
        for (int i = 0; i < 3; ++i)
#pragma unroll
            for (int j = 0; j < 3; ++j)
                D[i][j] = -(shd[3 + i * 3 + j][b] + shd[i][b]) / (float)TSUB;

        const int ns_raw = nspk_arr[b];
        const int n_spk = min(max(ns_raw, 1), 3);

        const int P[6][3] = {{0, 1, 2}, {0, 2, 1}, {1, 0, 2},
                             {1, 2, 0}, {2, 0, 1}, {2, 1, 0}};
        float best_s = 3.0e38f, best_d = 3.0e38f;
        for (int p = 0; p < 6; ++p) {
            bool valid = true;
            for (int s = 0; s < 3; ++s)
                if (!((P[p][s] < n_spk) || (s >= n_spk))) valid = false;
            if (!valid) continue;
            float ssum = 0.0f, dsum = 0.0f;
            for (int s = 0; s < 3; ++s) {
                if (s < n_spk) {
                    ssum += S[P[p][s]][s];
                    dsum += D[P[p][s]][s];
                }
            }
            float inv_n = 1.0f / (float)n_spk;
            best_s = fminf(best_s, -(ssum * inv_n));
            best_d = fminf(best_d, dsum * inv_n);
        }
        loss_s = best_s;
        loss_d = best_d;

        const int n_ex = min(ns_raw, 3);
        float be = 0.0f;
#pragma unroll
        for (int j = 0; j < 4; ++j) {
            float p = exist[b * 4 + j];
            float tgt = (j < n_ex) ? 1.0f : 0.0f;
            float lpv = fmaxf(logf(p), -100.0f);
            float l1v = fmaxf(logf(1.0f - p), -100.0f);
            be += -(tgt * lpv + (1.0f - tgt) * l1v);
        }
        loss_e = be;
    }

    // wave-0 reduction (lanes 32..63 hold zeros; other waves ignored)
    loss_s += __shfl_down(loss_s, 32);
    loss_s += __shfl_down(loss_s, 16);
    loss_s += __shfl_down(loss_s, 8);
    loss_s += __shfl_down(loss_s, 4);
    loss_s += __shfl_down(loss_s, 2);
    loss_s += __shfl_down(loss_s, 1);
    loss_d += __shfl_down(loss_d, 32);
    loss_d += __shfl_down(loss_d, 16);
    loss_d += __shfl_down(loss_d, 8);
    loss_d += __shfl_down(loss_d, 4);
    loss_d += __shfl_down(loss_d, 2);
    loss_d += __shfl_down(loss_d, 1);
    loss_e += __shfl_down(loss_e, 32);
    loss_e += __shfl_down(loss_e, 16);
    loss_e += __shfl_down(loss_e, 8);
    loss_e += __shfl_down(loss_e, 4);
    loss_e += __shfl_down(loss_e, 2);
    loss_e += __shfl_down(loss_e, 1);

    if (threadIdx.x == 0) {
        float ls = loss_s / (float)BB;
        float ld = loss_d / (float)BB;
        float le = loss_e / (float)(BB * 4);
        out[0] = ls + 0.2f * ld + 0.2f * le;  // total
        out[1] = ls;                           // loss_sisnr
        out[2] = ld;                           // loss_diar
        out[3] = le;                           // loss_exist
        out[4] = -ls;                          // mean_sisnr
    }
}

extern "C" void kernel_launch(void* const* d_in, const int* in_sizes, int n_in,
                              void* d_out, int out_size, void* d_ws, size_t ws_size,
                              hipStream_t stream) {
    const float* separated = (const float*)d_in[0];
    const float* diar      = (const float*)d_in[1];
    const float* exist     = (const float*)d_in[2];
    const float* sources   = (const float*)d_in[3];
    const float* labels    = (const float*)d_in[4];
    const int*   nspk      = (const int*)d_in[5];
    float* out = (float*)d_out;
    float* ws  = (float*)d_ws;

    stats_eendss<<<NBLK_TOTAL, 256, 0, stream>>>(separated, sources, diar,
                                                 labels, ws);
    finalize<<<1, 256, 0, stream>>>(ws, exist, nspk, out);
}